// Round 3
// baseline (658.426 us; speedup 1.0000x reference)
//
#include <hip/hip_runtime.h>
#include <hip/hip_bf16.h>
#include <stdint.h>

// ---------------------------------------------------------------------------
// LoRALinear (fp32 in / fp32 out):
//   C[M,N] = X[M,K] @ W[N,K]^T + bias[N] + 2.0 * (X @ A[R,K]^T) @ B[N,R]^T
// M=8192, N=4096, K=4096, R=16.
//
// Round-3 theory: device buffers are FP32 (per reference dtype). Rounds 1-2
// read them as bf16 -> random bf16-NaN patterns -> NaN output. No fp32 MFMA
// on CDNA4, so: fold W' = bf16(W + 2*B@A) into ws, cast X -> bf16 into ws,
// run the m97-structure bf16 MFMA GEMM, fp32 accumulate + fp32 epilogue.
// Paths keyed off ws_size (deterministic, graph-safe):
//   P1 (ws >= 101 MB): precast Xb + W'           -> gemm<true,true,false>
//   P2 (ws >=  34 MB): precast W', convert X in-kernel -> gemm<false,true,false>
//   P3 (ws >= 768 KB): no precast; LoRA via epilogue MFMA -> gemm<false,false,true>
// ---------------------------------------------------------------------------

typedef __bf16 bf16x8 __attribute__((ext_vector_type(8)));
typedef __bf16 bf16x4 __attribute__((ext_vector_type(4)));
typedef float f32x4 __attribute__((ext_vector_type(4)));

#define BM 128
#define BN 128
#define BK 32
#define LORA_R 16

__device__ __forceinline__ void async_copy16(const void* g, void* l) {
  // global -> LDS direct copy, 16 B/lane; LDS dest = wave-uniform base + lane*16.
  __builtin_amdgcn_global_load_lds(
      (const __attribute__((address_space(1))) void*)g,
      (__attribute__((address_space(3))) void*)l, 16, 0, 0);
}

// ---------------------------------------------------------------------------
// W'[n,k] = bf16( W[n,k] + 2 * sum_r B[n,r]*A[r,k] ).  grid (K/256, N), 256 thr.
// ---------------------------------------------------------------------------
__global__ void foldcast_w_kernel(const float* __restrict__ W,
                                  const float* __restrict__ A,   // [R,K]
                                  const float* __restrict__ Bl,  // [N,R]
                                  __hip_bfloat16* __restrict__ Wp, int K) {
  const int n = blockIdx.y;
  const int k = blockIdx.x * 256 + threadIdx.x;
  float acc = W[(size_t)n * K + k];
#pragma unroll
  for (int r = 0; r < LORA_R; ++r)
    acc += 2.0f * Bl[n * LORA_R + r] * A[(size_t)r * K + k];  // SCALING = 2.0
  Wp[(size_t)n * K + k] = __float2bfloat16(acc);
}

// ---------------------------------------------------------------------------
// Xb = bf16(X), 8 elements / thread.
// ---------------------------------------------------------------------------
__global__ void cast_x_kernel(const float* __restrict__ X,
                              __hip_bfloat16* __restrict__ Xb) {
  const size_t i = ((size_t)blockIdx.x * 256 + threadIdx.x) * 8;
  f32x4 a = *(const f32x4*)(X + i);
  f32x4 b = *(const f32x4*)(X + i + 4);
  bf16x8 o;
#pragma unroll
  for (int j = 0; j < 4; ++j) o[j] = (__bf16)a[j];
#pragma unroll
  for (int j = 0; j < 4; ++j) o[4 + j] = (__bf16)b[j];
  *(bf16x8*)(Xb + i) = o;
}

// ---------------------------------------------------------------------------
// P3 helpers: B32[n][r<16]=bf16(lB[n][r]) else 0 ; XA32[m] = [bf16(X@A^T), 0]
// ---------------------------------------------------------------------------
__global__ void padb32_kernel(const float* __restrict__ lB,
                              __hip_bfloat16* __restrict__ B32) {
  const int i = blockIdx.x * 256 + threadIdx.x;  // over N*32
  const int n = i >> 5, r = i & 31;
  B32[i] = (r < LORA_R) ? __float2bfloat16(lB[n * LORA_R + r])
                        : __float2bfloat16(0.0f);
}

__global__ __launch_bounds__(256) void xa_fp32_kernel(
    const float* __restrict__ X, const float* __restrict__ A,
    __hip_bfloat16* __restrict__ XA32, int K) {
  const int lane = threadIdx.x & 63;
  const int m = blockIdx.x * 4 + (threadIdx.x >> 6);
  float acc[LORA_R] = {};
  const size_t xrow = (size_t)m * K;
  for (int k0 = 0; k0 < K; k0 += 256) {
    const int k = k0 + lane * 4;
    f32x4 xv = *(const f32x4*)(X + xrow + k);
#pragma unroll
    for (int r = 0; r < LORA_R; ++r) {
      f32x4 av = *(const f32x4*)(A + (size_t)r * K + k);
      acc[r] += xv[0] * av[0] + xv[1] * av[1] + xv[2] * av[2] + xv[3] * av[3];
    }
  }
#pragma unroll
  for (int r = 0; r < LORA_R; ++r)
    for (int off = 32; off > 0; off >>= 1) acc[r] += __shfl_xor(acc[r], off, 64);
  if (lane == 0) {
#pragma unroll
    for (int r = 0; r < LORA_R; ++r)
      XA32[(size_t)m * 32 + r] = __float2bfloat16(acc[r]);
#pragma unroll
    for (int r = LORA_R; r < 32; ++r)
      XA32[(size_t)m * 32 + r] = __float2bfloat16(0.0f);
  }
}

// ---------------------------------------------------------------------------
// GEMM: C = X@Wop^T (+bias) (+2*XA32@B32^T if ELORA). 128x128 tile, BK=32,
// 4 waves each owning a 64x64 quadrant as 4x4 mfma_f32_16x16x32_bf16.
// XPRE/WPRE: operand is precast bf16 in global -> global_load_lds staging.
// Otherwise: operand is fp32 in global -> VGPR load + cvt + ds_write staging.
// ---------------------------------------------------------------------------
template <bool XPRE, bool WPRE, bool ELORA>
__global__ __launch_bounds__(256) void gemm_kernel(
    const void* __restrict__ Xv, const void* __restrict__ Wv,
    const float* __restrict__ bias,
    const __hip_bfloat16* __restrict__ XA32,  // [M,32] zero-padded (ELORA)
    const __hip_bfloat16* __restrict__ B32,   // [N,32] zero-padded (ELORA)
    float* __restrict__ Out, int M, int N, int K) {
  __shared__ __align__(16) unsigned short As[BM * BK];  // 8 KB, row stride 64 B
  __shared__ __align__(16) unsigned short Bs[BN * BK];  // 8 KB

  const int t = threadIdx.x;
  const int lane = t & 63;
  const int wave = t >> 6;
  const int m0 = blockIdx.y * BM;
  const int n0 = blockIdx.x * BN;
  const int wm = (wave >> 1) * 64;
  const int wn = (wave & 1) * 64;

  // Precast staging map (global_load_lds w=16): row = t>>2, colElem = (t&3)*8.
  const int srow = t >> 2;
  const int ka = (t & 3) * 8;
  // FP32 staging map: j in 0..3 -> row = j*32 + (t>>3), colFloat = (t&7)*4.
  const int f_r = t >> 3;
  const int f_c = (t & 7) * 4;

  char* smA = (char*)As;
  char* smB = (char*)Bs;
  const int waveByte = wave * 1024;

  f32x4 acc[4][4];
#pragma unroll
  for (int mi = 0; mi < 4; ++mi)
#pragma unroll
    for (int ni = 0; ni < 4; ++ni) acc[mi][ni] = (f32x4){0.f, 0.f, 0.f, 0.f};

  const unsigned short* aBase = As + (wm + (lane & 15)) * BK + (lane >> 4) * 8;
  const unsigned short* bBase = Bs + (wn + (lane & 15)) * BK + (lane >> 4) * 8;

  const int kIters = K / BK;
  for (int kt = 0; kt < kIters; ++kt) {
    const int gk = kt * BK;
    // ---- stage A (X) ----
    if constexpr (XPRE) {
      const __hip_bfloat16* Xb = (const __hip_bfloat16*)Xv;
      async_copy16(Xb + (size_t)(m0 + srow) * K + gk + ka, smA + waveByte);
      async_copy16(Xb + (size_t)(m0 + 64 + srow) * K + gk + ka, smA + 4096 + waveByte);
    } else {
      const float* Xf = (const float*)Xv;
#pragma unroll
      for (int j = 0; j < 4; ++j) {
        const int row = j * 32 + f_r;
        f32x4 v = *(const f32x4*)(Xf + (size_t)(m0 + row) * K + gk + f_c);
        bf16x4 p;
#pragma unroll
        for (int e = 0; e < 4; ++e) p[e] = (__bf16)v[e];
        *(bf16x4*)(smA + row * 64 + f_c * 2) = p;  // ds_write_b64
      }
    }
    // ---- stage B (W) ----
    if constexpr (WPRE) {
      const __hip_bfloat16* Wb = (const __hip_bfloat16*)Wv;
      async_copy16(Wb + (size_t)(n0 + srow) * K + gk + ka, smB + waveByte);
      async_copy16(Wb + (size_t)(n0 + 64 + srow) * K + gk + ka, smB + 4096 + waveByte);
    } else {
      const float* Wf = (const float*)Wv;
#pragma unroll
      for (int j = 0; j < 4; ++j) {
        const int row = j * 32 + f_r;
        f32x4 v = *(const f32x4*)(Wf + (size_t)(n0 + row) * K + gk + f_c);
        bf16x4 p;
#pragma unroll
        for (int e = 0; e < 4; ++e) p[e] = (__bf16)v[e];
        *(bf16x4*)(smB + row * 64 + f_c * 2) = p;
      }
    }
    __syncthreads();  // drains vmcnt (global_load_lds) + lgkmcnt (ds_write)

    bf16x8 af[4], bfv[4];
#pragma unroll
    for (int i = 0; i < 4; ++i) {
      af[i] = *(const bf16x8*)(aBase + i * 16 * BK);  // ds_read_b128
      bfv[i] = *(const bf16x8*)(bBase + i * 16 * BK);
    }
#pragma unroll
    for (int mi = 0; mi < 4; ++mi)
#pragma unroll
      for (int ni = 0; ni < 4; ++ni)
        acc[mi][ni] = __builtin_amdgcn_mfma_f32_16x16x32_bf16(
            af[mi], bfv[ni], acc[mi][ni], 0, 0, 0);
    __syncthreads();
  }

  // ---- epilogue: C/D layout col=lane&15, row=(lane>>4)*4+reg ----
  const int col = lane & 15;
  const int quad = lane >> 4;
  const int rbase = quad * 4;

  bf16x8 xaf[4], blf[4];
  if constexpr (ELORA) {
#pragma unroll
    for (int mi = 0; mi < 4; ++mi)
      xaf[mi] = *(const bf16x8*)(XA32 + (size_t)(m0 + wm + mi * 16 + col) * 32 + quad * 8);
#pragma unroll
    for (int ni = 0; ni < 4; ++ni)
      blf[ni] = *(const bf16x8*)(B32 + (size_t)(n0 + wn + ni * 16 + col) * 32 + quad * 8);
  }

  const f32x4 zero4 = (f32x4){0.f, 0.f, 0.f, 0.f};
#pragma unroll
  for (int ni = 0; ni < 4; ++ni) {
    const int n = n0 + wn + ni * 16 + col;
    const float bv = bias[n];
#pragma unroll
    for (int mi = 0; mi < 4; ++mi) {
      f32x4 u = zero4;
      if constexpr (ELORA)
        u = __builtin_amdgcn_mfma_f32_16x16x32_bf16(xaf[mi], blf[ni], zero4, 0, 0, 0);
      const size_t rowBase = (size_t)(m0 + wm + mi * 16 + rbase) * N + n;
#pragma unroll
      for (int r = 0; r < 4; ++r)
        Out[rowBase + (size_t)r * N] = acc[mi][ni][r] + bv + 2.0f * u[r];
    }
  }
}

// ---------------------------------------------------------------------------
extern "C" void kernel_launch(void* const* d_in, const int* in_sizes, int n_in,
                              void* d_out, int out_size, void* d_ws, size_t ws_size,
                              hipStream_t stream) {
  const float* X    = (const float*)d_in[0];  // [B,S,Din] fp32
  const float* W    = (const float*)d_in[1];  // [Dout,Din] fp32
  const float* bias = (const float*)d_in[2];  // [Dout] fp32
  const float* lA   = (const float*)d_in[3];  // [R,Din] fp32
  const float* lB   = (const float*)d_in[4];  // [Dout,R] fp32
  float* Out = (float*)d_out;

  const int K = in_sizes[3] / LORA_R;  // 4096
  const int N = in_sizes[2];           // 4096
  const int M = in_sizes[0] / K;       // 8192

  const size_t xbBytes = (size_t)M * K * 2;  // 67,108,864
  const size_t wpBytes = (size_t)N * K * 2;  // 33,554,432
  const dim3 gGrid(N / BN, M / BM);

  if (ws_size >= xbBytes + wpBytes) {
    // P1: precast X and fold+cast W'.
    __hip_bfloat16* Xb = (__hip_bfloat16*)d_ws;
    __hip_bfloat16* Wp = (__hip_bfloat16*)((char*)d_ws + xbBytes);
    cast_x_kernel<<<dim3(((size_t)M * K) / (256 * 8)), 256, 0, stream>>>(X, Xb);
    foldcast_w_kernel<<<dim3(K / 256, N), 256, 0, stream>>>(W, lA, lB, Wp, K);
    gemm_kernel<true, true, false><<<gGrid, 256, 0, stream>>>(
        Xb, Wp, bias, nullptr, nullptr, Out, M, N, K);
  } else if (ws_size >= wpBytes) {
    // P2: fold+cast W' only; convert X tiles in-kernel.
    __hip_bfloat16* Wp = (__hip_bfloat16*)d_ws;
    foldcast_w_kernel<<<dim3(K / 256, N), 256, 0, stream>>>(W, lA, lB, Wp, K);
    gemm_kernel<false, true, false><<<gGrid, 256, 0, stream>>>(
        X, Wp, bias, nullptr, nullptr, Out, M, N, K);
  } else {
    // P3: tiny ws — LoRA via epilogue MFMA, both operands converted in-kernel.
    __hip_bfloat16* XA32 = (__hip_bfloat16*)d_ws;           // M*32*2 = 512 KB
    __hip_bfloat16* B32  = XA32 + (size_t)M * 32;           // N*32*2 = 256 KB
    padb32_kernel<<<dim3((N * 32) / 256), 256, 0, stream>>>(lB, B32);
    xa_fp32_kernel<<<dim3(M / 4), 256, 0, stream>>>(X, lA, XA32, K);
    gemm_kernel<false, false, true><<<gGrid, 256, 0, stream>>>(
        X, W, bias, XA32, B32, Out, M, N, K);
  }
}